// Round 8
// baseline (182.509 us; speedup 1.0000x reference)
//
#include <hip/hip_runtime.h>
#include <math.h>

// B=16,H=14,W=14,D=512, L=32, HID=512, A=512. fp32 in/out; bf16 in MFMA GEMM phases.
// Single cooperative-style mega-kernel: 224 blocks x 256 threads, 4 phases with
// hand-rolled agent-scope grid barriers (counters in d_ws, memset per launch).
#define NBLK 224

typedef __attribute__((ext_vector_type(8))) short short8;
typedef __attribute__((ext_vector_type(4))) float f32x4;

__device__ __forceinline__ unsigned f2bf_u(float x) {
    union { float f; unsigned u; } c; c.f = x;
    return (c.u + 0x7FFFu + ((c.u >> 16) & 1u)) >> 16;   // RNE, finite inputs
}
__device__ __forceinline__ unsigned short f2bf(float x) { return (unsigned short)f2bf_u(x); }
__device__ __forceinline__ unsigned pack2(float lo, float hi) {
    return f2bf_u(lo) | (f2bf_u(hi) << 16);
}
__device__ __forceinline__ uint4 pack8(const float4 a, const float4 b) {
    uint4 r;
    r.x = pack2(a.x, a.y); r.y = pack2(a.z, a.w);
    r.z = pack2(b.x, b.y); r.w = pack2(b.z, b.w);
    return r;
}

__device__ __forceinline__ void gridbar(int* bar, int idx) {
    __syncthreads();
    if (threadIdx.x == 0) {
        __hip_atomic_fetch_add(&bar[idx], 1, __ATOMIC_ACQ_REL, __HIP_MEMORY_SCOPE_AGENT);
        while (__hip_atomic_load(&bar[idx], __ATOMIC_ACQUIRE, __HIP_MEMORY_SCOPE_AGENT) < NBLK) {
            __builtin_amdgcn_s_sleep(2);
        }
    }
    __syncthreads();
}

// ---- GEMM phase: C = A(512,512)·B(512,512)^T + bias[n] [* hmul] ; bf16 MFMA ----
// 256 tiles of 32x32 looped over NBLK blocks; 4 waves split K (128 each) + LDS reduce.
template<int MODE>
__device__ __forceinline__ void gemm_phase(
    const float* __restrict__ Af, const unsigned short* __restrict__ Ab,
    const float* __restrict__ Bf, const float* __restrict__ bias,
    const float* __restrict__ hmul, float* __restrict__ C, char* smem, int bid)
{
    uint4* As = (uint4*)smem;               // 2048 slots (32KB)
    uint4* Bs = (uint4*)(smem + 32768);     // 2048 slots (32KB)
    float* red = (float*)smem;              // overlays As after sync (16KB)
    const int tid = threadIdx.x;

    for (int tile = bid; tile < 256; tile += NBLK) {
        const int m0 = (tile >> 4) * 32, n0 = (tile & 15) * 32;
        __syncthreads();                    // smem safe to reuse
        #pragma unroll
        for (int j = 0; j < 8; ++j) {
            const int S = tid + 256 * j;
            const int i = S >> 6, ln = S & 63;
            const int t = i & 1, s = i >> 1;
            const int row  = t * 16 + (ln & 15);
            const int col8 = s * 4 + (ln >> 4);
            uint4 av;
            if (MODE == 0) {
                const float* ap = Af + (size_t)(m0 + row) * 512 + col8 * 8;
                av = pack8(*(const float4*)ap, *(const float4*)(ap + 4));
            } else {
                av = *(const uint4*)(Ab + (size_t)(m0 + row) * 512 + col8 * 8);
            }
            const float* bp = Bf + (size_t)(n0 + row) * 512 + col8 * 8;
            As[S] = av;
            Bs[S] = pack8(*(const float4*)bp, *(const float4*)(bp + 4));
        }
        __syncthreads();

        const int w = tid >> 6, ln = tid & 63;
        f32x4 acc[4];                        // fo = tm*2+tn
        #pragma unroll
        for (int fo = 0; fo < 4; ++fo) acc[fo] = (f32x4){0.f,0.f,0.f,0.f};
        #pragma unroll
        for (int sl = 0; sl < 4; ++sl) {
            const int s = 4 * w + sl;
            const short8 a0 = *(const short8*)&As[(2*s+0)*64 + ln];
            const short8 a1 = *(const short8*)&As[(2*s+1)*64 + ln];
            const short8 b0 = *(const short8*)&Bs[(2*s+0)*64 + ln];
            const short8 b1 = *(const short8*)&Bs[(2*s+1)*64 + ln];
            acc[0] = __builtin_amdgcn_mfma_f32_16x16x32_bf16(a0, b0, acc[0], 0, 0, 0);
            acc[1] = __builtin_amdgcn_mfma_f32_16x16x32_bf16(a0, b1, acc[1], 0, 0, 0);
            acc[2] = __builtin_amdgcn_mfma_f32_16x16x32_bf16(a1, b0, acc[2], 0, 0, 0);
            acc[3] = __builtin_amdgcn_mfma_f32_16x16x32_bf16(a1, b1, acc[3], 0, 0, 0);
        }
        __syncthreads();                     // done reading As/Bs
        #pragma unroll
        for (int fo = 0; fo < 4; ++fo)
            #pragma unroll
            for (int r = 0; r < 4; ++r)
                red[w*1024 + fo*256 + r*64 + ln] = acc[fo][r];
        __syncthreads();
        #pragma unroll
        for (int j = 0; j < 4; ++j) {
            const int o = tid + 256 * j;
            float v = red[o] + red[1024 + o] + red[2048 + o] + red[3072 + o];
            const int fo = o >> 8, r = (o >> 6) & 3, l2 = o & 63;
            // C/D layout: col = lane&15, row = (lane>>4)*4 + reg [m89-verified]
            const int m = m0 + (fo >> 1) * 16 + ((l2 >> 4) << 2) + r;
            const int n = n0 + (fo & 1) * 16 + (l2 & 15);
            v += bias[n];
            if (MODE == 1) v *= hmul[(size_t)m * 512 + n];
            C[(size_t)m * 512 + n] = v;
        }
    }
}

// ---- scores phase: block bid -> (b = bid/14, ptile = bid%14). ----
// f,w in registers (8 float4 each); hlin staged flat in LDS; acc[32]/thread.
__device__ __forceinline__ void scores_phase(
    const float* __restrict__ maps, const float* __restrict__ hlin,
    const float* __restrict__ W_rect, const float* __restrict__ b_rect,
    float* __restrict__ scores_out, char* smem, int bid)
{
    float* hls  = (float*)smem;              // 32*512 fp32 = 64KB
    float* redb = (float*)smem;              // overlays hls after main loop
    const int tid = threadIdx.x;
    const int b = bid / 14, p0 = (bid % 14) * 14;
    const int kc = tid >> 4, pslot = tid & 15;
    const int p = p0 + (pslot < 14 ? pslot : 13);

    __syncthreads();
    const float4* hg = (const float4*)(hlin + (size_t)b * 32 * 512);
    float4* h4 = (float4*)hls;
    #pragma unroll
    for (int j = 0; j < 16; ++j) h4[tid + 256 * j] = hg[tid + 256 * j];

    float4 fr[8], wr[8];
    const float* fb = maps + ((size_t)b * 196 + p) * 512 + kc * 32;
    const float* wb = W_rect + kc * 32;
    #pragma unroll
    for (int j = 0; j < 8; ++j) {
        fr[j] = *(const float4*)(fb + 4 * j);
        wr[j] = *(const float4*)(wb + 4 * j);
    }
    __syncthreads();

    float acc[32];
    for (int l = 0; l < 32; ++l) {
        const float* hrow = hls + l * 512 + kc * 32;
        float s0 = 0.f, s1 = 0.f, s2 = 0.f, s3 = 0.f;
        #pragma unroll
        for (int j = 0; j < 8; ++j) {
            const float4 h = *(const float4*)(hrow + 4 * j);
            const float4 f = fr[j], w = wr[j];
            s0 += fmaxf(f.x + h.x, 0.f) * w.x;
            s1 += fmaxf(f.y + h.y, 0.f) * w.y;
            s2 += fmaxf(f.z + h.z, 0.f) * w.z;
            s3 += fmaxf(f.w + h.w, 0.f) * w.w;
        }
        acc[l] = (s0 + s1) + (s2 + s3);
    }
    __syncthreads();                         // done reading hls
    // bank-rotated partial layout: addr = pslot*545 + l*17 + kc  (545%32=1 -> spread)
    #pragma unroll 4
    for (int l = 0; l < 32; ++l)
        redb[pslot * 545 + l * 17 + kc] = acc[l];
    __syncthreads();
    const float br = b_rect[0];
    for (int q = tid; q < 448; q += 256) {
        const int pp = q >> 5, l = q & 31;
        const float* rb = redb + pp * 545 + l * 17;
        float s = 0.f;
        #pragma unroll
        for (int k = 0; k < 16; ++k) s += rb[k];
        scores_out[((size_t)b * 32 + l) * 196 + p0 + pp] = s + br;
    }
}

// ---- softmax + ctx phase: 256 tiles (16 b x 16 dtiles) looped over NBLK blocks ----
__device__ __forceinline__ void softmax_ctx_phase(
    const float* __restrict__ maps, const float* __restrict__ scores,
    float* __restrict__ attn_out, unsigned short* __restrict__ ctx_out,
    char* smem, int bid)
{
    float* ft = (float*)smem;                // [196][36] = 28224 B
    float* at = (float*)(smem + 28224);      // [32][204] = 26112 B
    const int tid = threadIdx.x;

    for (int tile = bid; tile < 256; tile += NBLK) {
        const int b = tile >> 4, d0 = (tile & 15) * 32;
        __syncthreads();
        const float* fbase = maps + (size_t)b * 196 * 512 + d0;
        for (int fidx = tid; fidx < 1568; fidx += 256) {   // 196*32/4
            const int pp = fidx >> 3, q = fidx & 7;
            *(float4*)&ft[pp * 36 + q * 4] = *(const float4*)(fbase + (size_t)pp * 512 + q * 4);
        }
        const float4* sbase4 = (const float4*)(scores + (size_t)b * 32 * 196);
        for (int fidx = tid; fidx < 1568; fidx += 256) {   // 32 rows x 49 float4
            const int r = fidx / 49, c4 = fidx - r * 49;
            *(float4*)&at[r * 204 + c4 * 4] = sbase4[fidx];
        }
        __syncthreads();

        const int wave = tid >> 6, lane = tid & 63;
        #pragma unroll
        for (int rr = 0; rr < 8; ++rr) {
            const int row = wave * 8 + rr;
            float v[4];
            #pragma unroll
            for (int i = 0; i < 4; ++i) {
                const int pp = lane + 64 * i;
                v[i] = (pp < 196) ? at[row * 204 + pp] : -INFINITY;
            }
            float m = fmaxf(fmaxf(v[0], v[1]), fmaxf(v[2], v[3]));
            for (int off = 32; off > 0; off >>= 1) m = fmaxf(m, __shfl_down(m, off));
            m = __shfl(m, 0);
            float e[4], s = 0.f;
            #pragma unroll
            for (int i = 0; i < 4; ++i) {
                const int pp = lane + 64 * i;
                e[i] = (pp < 196) ? __expf(v[i] - m) : 0.f;
                s += e[i];
            }
            for (int off = 32; off > 0; off >>= 1) s += __shfl_down(s, off);
            s = __shfl(s, 0);
            const float inv = 1.f / s;
            #pragma unroll
            for (int i = 0; i < 4; ++i) {
                const int pp = lane + 64 * i;
                if (pp < 196) at[row * 204 + pp] = e[i] * inv;
            }
        }
        __syncthreads();

        if ((tile & 15) == 0) {
            float4* ao4 = (float4*)(attn_out + (size_t)b * 32 * 196);
            for (int fidx = tid; fidx < 1568; fidx += 256) {
                const int r = fidx / 49, c4 = fidx - r * 49;
                ao4[fidx] = *(const float4*)&at[r * 204 + c4 * 4];
            }
        }

        const int l = tid >> 3, d4 = tid & 7;
        float ax = 0.f, ay = 0.f, az = 0.f, aw = 0.f;
        for (int p4 = 0; p4 < 49; ++p4) {
            const float4 a4 = *(const float4*)&at[l * 204 + p4 * 4];
            const float4 f0 = *(const float4*)&ft[(p4 * 4 + 0) * 36 + d4 * 4];
            const float4 f1 = *(const float4*)&ft[(p4 * 4 + 1) * 36 + d4 * 4];
            const float4 f2 = *(const float4*)&ft[(p4 * 4 + 2) * 36 + d4 * 4];
            const float4 f3 = *(const float4*)&ft[(p4 * 4 + 3) * 36 + d4 * 4];
            ax += a4.x * f0.x + a4.y * f1.x + a4.z * f2.x + a4.w * f3.x;
            ay += a4.x * f0.y + a4.y * f1.y + a4.z * f2.y + a4.w * f3.y;
            az += a4.x * f0.z + a4.y * f1.z + a4.z * f2.z + a4.w * f3.z;
            aw += a4.x * f0.w + a4.y * f1.w + a4.z * f2.w + a4.w * f3.w;
        }
        ushort4 o;
        o.x = f2bf(ax); o.y = f2bf(ay); o.z = f2bf(az); o.w = f2bf(aw);
        *(ushort4*)(ctx_out + ((size_t)b * 32 + l) * 512 + d0 + d4 * 4) = o;
        __syncthreads();                     // at/ft reads done before next tile
    }
}

__global__ __launch_bounds__(256) void coatt_mega_kernel(
    const float* __restrict__ maps, const float* __restrict__ hiddens,
    const float* __restrict__ W_hidden, const float* __restrict__ b_hidden,
    const float* __restrict__ W_rect, const float* __restrict__ b_rect,
    const float* __restrict__ W_co, const float* __restrict__ b_co,
    float* __restrict__ out_co, float* __restrict__ out_attn,
    float* __restrict__ scores, unsigned short* __restrict__ ctx16,
    int* __restrict__ bar)
{
    __shared__ __align__(16) char smem[65536];
    const int bid = blockIdx.x;

    // Phase A: hlin = hiddens @ W_hidden^T + b_hidden -> out_co (temp)
    gemm_phase<0>(hiddens, (const unsigned short*)nullptr, W_hidden, b_hidden,
                  (const float*)nullptr, out_co, smem, bid);
    gridbar(bar, 0);
    // Phase B: raw scores -> ws
    scores_phase(maps, out_co, W_rect, b_rect, scores, smem, bid);
    gridbar(bar, 1);
    // Phase C: softmax (-> out_attn) + ctx (bf16 -> ws)
    softmax_ctx_phase(maps, scores, out_attn, ctx16, smem, bid);
    gridbar(bar, 2);
    // Phase D: out_co = (ctx @ W_co^T + b_co) * hiddens
    gemm_phase<1>((const float*)nullptr, ctx16, W_co, b_co, hiddens, out_co, smem, bid);
}

extern "C" void kernel_launch(void* const* d_in, const int* in_sizes, int n_in,
                              void* d_out, int out_size, void* d_ws, size_t ws_size,
                              hipStream_t stream)
{
    const float* maps     = (const float*)d_in[0];
    const float* hiddens  = (const float*)d_in[1];
    const float* W_hidden = (const float*)d_in[2];
    const float* b_hidden = (const float*)d_in[3];
    const float* W_rect   = (const float*)d_in[4];
    const float* b_rect   = (const float*)d_in[5];
    const float* W_co     = (const float*)d_in[6];
    const float* b_co     = (const float*)d_in[7];

    float* out_co   = (float*)d_out;                    // (512,512): hlin, then final
    float* out_attn = out_co + (size_t)512 * 512;       // (512,196)

    char* ws = (char*)d_ws;
    float*          scores = (float*)(ws);                          // 401 KB
    unsigned short* ctx16  = (unsigned short*)(ws + (1 << 20));     // 512 KB
    int*            bar    = (int*)(ws + (4 << 20));                // 64 B

    hipMemsetAsync(bar, 0, 64, stream);
    hipLaunchKernelGGL(coatt_mega_kernel, dim3(NBLK), dim3(256), 0, stream,
                       maps, hiddens, W_hidden, b_hidden, W_rect, b_rect,
                       W_co, b_co, out_co, out_attn, scores, ctx16, bar);
}

// Round 9
// 180.433 us; speedup vs baseline: 1.0115x; 1.0115x over previous
//
#include <hip/hip_runtime.h>
#include <math.h>

// B=16,H=14,W=14,D=512, L=32, HID=512, A=512. fp32 in/out; bf16 in MFMA GEMM phases.
// Single-node mega-kernel: 256 blocks x 256 threads, 4 phases with a master-block
// grid barrier (private flags + go; no atomic RMW; no memset needed since the 0xAA
// ws poison reads as a negative int and epochs are monotonic positives).
#define NBLK 256

typedef __attribute__((ext_vector_type(8))) short short8;
typedef __attribute__((ext_vector_type(4))) float f32x4;

__device__ __forceinline__ unsigned f2bf_u(float x) {
    union { float f; unsigned u; } c; c.f = x;
    return (c.u + 0x7FFFu + ((c.u >> 16) & 1u)) >> 16;   // RNE, finite inputs
}
__device__ __forceinline__ unsigned short f2bf(float x) { return (unsigned short)f2bf_u(x); }
__device__ __forceinline__ unsigned pack2(float lo, float hi) {
    return f2bf_u(lo) | (f2bf_u(hi) << 16);
}
__device__ __forceinline__ uint4 pack8(const float4 a, const float4 b) {
    uint4 r;
    r.x = pack2(a.x, a.y); r.y = pack2(a.z, a.w);
    r.z = pack2(b.x, b.y); r.w = pack2(b.z, b.w);
    return r;
}

// flags[i*32] for block i (128B apart); go at flags[NBLK*32 + 32].
__device__ __forceinline__ void gridbar(int* flags, int* go, int epoch) {
    __syncthreads();
    if (threadIdx.x == 0)
        __hip_atomic_store(&flags[blockIdx.x * 32], epoch, __ATOMIC_RELEASE, __HIP_MEMORY_SCOPE_AGENT);
    if (blockIdx.x == 0) {
        while (__hip_atomic_load(&flags[threadIdx.x * 32], __ATOMIC_ACQUIRE,
                                 __HIP_MEMORY_SCOPE_AGENT) < epoch) { __builtin_amdgcn_s_sleep(1); }
        __syncthreads();
        if (threadIdx.x == 0)
            __hip_atomic_store(go, epoch, __ATOMIC_RELEASE, __HIP_MEMORY_SCOPE_AGENT);
    }
    if (threadIdx.x == 0) {
        while (__hip_atomic_load(go, __ATOMIC_ACQUIRE, __HIP_MEMORY_SCOPE_AGENT) < epoch) {
            __builtin_amdgcn_s_sleep(1);
        }
    }
    __syncthreads();
}

// ---- GEMM phase: C = A(512,512)·B(512,512)^T + bias[n] [* hmul] ; bf16 MFMA ----
// 256 tiles of 32x32, exactly one per block; 4 waves split K (128 each) + LDS reduce.
template<int MODE>
__device__ __forceinline__ void gemm_phase(
    const float* __restrict__ Af, const unsigned short* __restrict__ Ab,
    const float* __restrict__ Bf, const float* __restrict__ bias,
    const float* __restrict__ hmul, float* __restrict__ C, char* smem, int bid)
{
    uint4* As = (uint4*)smem;               // 2048 slots (32KB)
    uint4* Bs = (uint4*)(smem + 32768);     // 2048 slots (32KB)
    float* red = (float*)smem;              // overlays As after sync (16KB)
    const int tid = threadIdx.x;

    const int m0 = (bid >> 4) * 32, n0 = (bid & 15) * 32;
    __syncthreads();
    #pragma unroll
    for (int j = 0; j < 8; ++j) {
        const int S = tid + 256 * j;
        const int i = S >> 6, ln = S & 63;
        const int t = i & 1, s = i >> 1;
        const int row  = t * 16 + (ln & 15);
        const int col8 = s * 4 + (ln >> 4);
        uint4 av;
        if (MODE == 0) {
            const float* ap = Af + (size_t)(m0 + row) * 512 + col8 * 8;
            av = pack8(*(const float4*)ap, *(const float4*)(ap + 4));
        } else {
            av = *(const uint4*)(Ab + (size_t)(m0 + row) * 512 + col8 * 8);
        }
        const float* bp = Bf + (size_t)(n0 + row) * 512 + col8 * 8;
        As[S] = av;
        Bs[S] = pack8(*(const float4*)bp, *(const float4*)(bp + 4));
    }
    __syncthreads();

    const int w = tid >> 6, ln = tid & 63;
    f32x4 acc[4];                            // fo = tm*2+tn
    #pragma unroll
    for (int fo = 0; fo < 4; ++fo) acc[fo] = (f32x4){0.f,0.f,0.f,0.f};
    #pragma unroll
    for (int sl = 0; sl < 4; ++sl) {
        const int s = 4 * w + sl;
        const short8 a0 = *(const short8*)&As[(2*s+0)*64 + ln];
        const short8 a1 = *(const short8*)&As[(2*s+1)*64 + ln];
        const short8 b0 = *(const short8*)&Bs[(2*s+0)*64 + ln];
        const short8 b1 = *(const short8*)&Bs[(2*s+1)*64 + ln];
        acc[0] = __builtin_amdgcn_mfma_f32_16x16x32_bf16(a0, b0, acc[0], 0, 0, 0);
        acc[1] = __builtin_amdgcn_mfma_f32_16x16x32_bf16(a0, b1, acc[1], 0, 0, 0);
        acc[2] = __builtin_amdgcn_mfma_f32_16x16x32_bf16(a1, b0, acc[2], 0, 0, 0);
        acc[3] = __builtin_amdgcn_mfma_f32_16x16x32_bf16(a1, b1, acc[3], 0, 0, 0);
    }
    __syncthreads();                         // done reading As/Bs
    #pragma unroll
    for (int fo = 0; fo < 4; ++fo)
        #pragma unroll
        for (int r = 0; r < 4; ++r)
            red[w*1024 + fo*256 + r*64 + ln] = acc[fo][r];
    __syncthreads();
    #pragma unroll
    for (int j = 0; j < 4; ++j) {
        const int o = tid + 256 * j;
        float v = red[o] + red[1024 + o] + red[2048 + o] + red[3072 + o];
        const int fo = o >> 8, r = (o >> 6) & 3, l2 = o & 63;
        // C/D layout: col = lane&15, row = (lane>>4)*4 + reg [m89-verified]
        const int m = m0 + (fo >> 1) * 16 + ((l2 >> 4) << 2) + r;
        const int n = n0 + (fo & 1) * 16 + (l2 & 15);
        v += bias[n];
        if (MODE == 1) v *= hmul[(size_t)m * 512 + n];
        C[(size_t)m * 512 + n] = v;
    }
}

// ---- scores phase: bid<224 -> (b = bid/14, ptile = bid%14). ----
// f,w in registers; hlin staged flat in LDS; column rotation (j+2kc)&7 kills conflicts.
__device__ __forceinline__ void scores_phase(
    const float* __restrict__ maps, const float* __restrict__ hlin,
    const float* __restrict__ W_rect, const float* __restrict__ b_rect,
    float* __restrict__ scores_out, char* smem, int bid)
{
    float* hls  = (float*)smem;              // 32*512 fp32 = 64KB
    float* redb = (float*)smem;              // overlays hls after main loop
    const int tid = threadIdx.x;
    const int b = bid / 14, p0 = (bid % 14) * 14;
    const int kc = tid >> 4, pslot = tid & 15;
    const int p = p0 + (pslot < 14 ? pslot : 13);

    __syncthreads();
    const float4* hg = (const float4*)(hlin + (size_t)b * 32 * 512);
    float4* h4 = (float4*)hls;
    #pragma unroll
    for (int j = 0; j < 16; ++j) h4[tid + 256 * j] = hg[tid + 256 * j];

    int cofs[8];
    float4 fr[8], wr[8];
    const float* fb = maps + ((size_t)b * 196 + p) * 512 + kc * 32;
    const float* wb = W_rect + kc * 32;
    #pragma unroll
    for (int j = 0; j < 8; ++j) {
        cofs[j] = 4 * ((j + 2 * kc) & 7);
        fr[j] = *(const float4*)(fb + cofs[j]);
        wr[j] = *(const float4*)(wb + cofs[j]);
    }
    __syncthreads();

    float acc[32];
    for (int l = 0; l < 32; ++l) {
        const float* hrow = hls + l * 512 + kc * 32;
        float s0 = 0.f, s1 = 0.f, s2 = 0.f, s3 = 0.f;
        #pragma unroll
        for (int j = 0; j < 8; ++j) {
            const float4 h = *(const float4*)(hrow + cofs[j]);
            const float4 f = fr[j], w = wr[j];
            s0 += fmaxf(f.x + h.x, 0.f) * w.x;
            s1 += fmaxf(f.y + h.y, 0.f) * w.y;
            s2 += fmaxf(f.z + h.z, 0.f) * w.z;
            s3 += fmaxf(f.w + h.w, 0.f) * w.w;
        }
        acc[l] = (s0 + s1) + (s2 + s3);
    }
    __syncthreads();                         // done reading hls
    // bank-rotated partial layout: addr = pslot*545 + l*17 + kc
    #pragma unroll 4
    for (int l = 0; l < 32; ++l)
        redb[pslot * 545 + l * 17 + kc] = acc[l];
    __syncthreads();
    const float br = b_rect[0];
    for (int q = tid; q < 448; q += 256) {
        const int pp = q >> 5, l = q & 31;
        const float* rb = redb + pp * 545 + l * 17;
        float s = 0.f;
        #pragma unroll
        for (int k = 0; k < 16; ++k) s += rb[k];
        scores_out[((size_t)b * 32 + l) * 196 + p0 + pp] = s + br;
    }
}

// ---- softmax + ctx phase: 256 tiles (16 b x 16 dtiles), one per block ----
__device__ __forceinline__ void softmax_ctx_phase(
    const float* __restrict__ maps, const float* __restrict__ scores,
    float* __restrict__ attn_out, unsigned short* __restrict__ ctx_out,
    char* smem, int bid)
{
    float* ft = (float*)smem;                // [196][36] = 28224 B
    float* at = (float*)(smem + 28224);      // [32][204] = 26112 B
    const int tid = threadIdx.x;

    const int b = bid >> 4, d0 = (bid & 15) * 32;
    __syncthreads();
    const float* fbase = maps + (size_t)b * 196 * 512 + d0;
    for (int fidx = tid; fidx < 1568; fidx += 256) {   // 196*32/4
        const int pp = fidx >> 3, q = fidx & 7;
        *(float4*)&ft[pp * 36 + q * 4] = *(const float4*)(fbase + (size_t)pp * 512 + q * 4);
    }
    const float4* sbase4 = (const float4*)(scores + (size_t)b * 32 * 196);
    for (int fidx = tid; fidx < 1568; fidx += 256) {   // 32 rows x 49 float4
        const int r = fidx / 49, c4 = fidx - r * 49;
        *(float4*)&at[r * 204 + c4 * 4] = sbase4[fidx];
    }
    __syncthreads();

    const int wave = tid >> 6, lane = tid & 63;
    #pragma unroll
    for (int rr = 0; rr < 8; ++rr) {
        const int row = wave * 8 + rr;
        float v[4];
        #pragma unroll
        for (int i = 0; i < 4; ++i) {
            const int pp = lane + 64 * i;
            v[i] = (pp < 196) ? at[row * 204 + pp] : -INFINITY;
        }
        float m = fmaxf(fmaxf(v[0], v[1]), fmaxf(v[2], v[3]));
        for (int off = 32; off > 0; off >>= 1) m = fmaxf(m, __shfl_down(m, off));
        m = __shfl(m, 0);
        float e[4], s = 0.f;
        #pragma unroll
        for (int i = 0; i < 4; ++i) {
            const int pp = lane + 64 * i;
            e[i] = (pp < 196) ? __expf(v[i] - m) : 0.f;
            s += e[i];
        }
        for (int off = 32; off > 0; off >>= 1) s += __shfl_down(s, off);
        s = __shfl(s, 0);
        const float inv = 1.f / s;
        #pragma unroll
        for (int i = 0; i < 4; ++i) {
            const int pp = lane + 64 * i;
            if (pp < 196) at[row * 204 + pp] = e[i] * inv;
        }
    }
    __syncthreads();

    if ((bid & 15) == 0) {
        float4* ao4 = (float4*)(attn_out + (size_t)b * 32 * 196);
        for (int fidx = tid; fidx < 1568; fidx += 256) {
            const int r = fidx / 49, c4 = fidx - r * 49;
            ao4[fidx] = *(const float4*)&at[r * 204 + c4 * 4];
        }
    }

    const int l = tid >> 3, d4 = tid & 7;
    float ax = 0.f, ay = 0.f, az = 0.f, aw = 0.f;
    for (int p4 = 0; p4 < 49; ++p4) {
        const float4 a4 = *(const float4*)&at[l * 204 + p4 * 4];
        const float4 f0 = *(const float4*)&ft[(p4 * 4 + 0) * 36 + d4 * 4];
        const float4 f1 = *(const float4*)&ft[(p4 * 4 + 1) * 36 + d4 * 4];
        const float4 f2 = *(const float4*)&ft[(p4 * 4 + 2) * 36 + d4 * 4];
        const float4 f3 = *(const float4*)&ft[(p4 * 4 + 3) * 36 + d4 * 4];
        ax += a4.x * f0.x + a4.y * f1.x + a4.z * f2.x + a4.w * f3.x;
        ay += a4.x * f0.y + a4.y * f1.y + a4.z * f2.y + a4.w * f3.y;
        az += a4.x * f0.z + a4.y * f1.z + a4.z * f2.z + a4.w * f3.z;
        aw += a4.x * f0.w + a4.y * f1.w + a4.z * f2.w + a4.w * f3.w;
    }
    ushort4 o;
    o.x = f2bf(ax); o.y = f2bf(ay); o.z = f2bf(az); o.w = f2bf(aw);
    *(ushort4*)(ctx_out + ((size_t)b * 32 + l) * 512 + d0 + d4 * 4) = o;
    __syncthreads();
}

__global__ __launch_bounds__(256) void coatt_mega_kernel(
    const float* __restrict__ maps, const float* __restrict__ hiddens,
    const float* __restrict__ W_hidden, const float* __restrict__ b_hidden,
    const float* __restrict__ W_rect, const float* __restrict__ b_rect,
    const float* __restrict__ W_co, const float* __restrict__ b_co,
    float* __restrict__ out_co, float* __restrict__ out_attn,
    float* __restrict__ scores, unsigned short* __restrict__ ctx16,
    int* __restrict__ flags, int* __restrict__ go)
{
    __shared__ __align__(16) char smem[65536];
    const int bid = blockIdx.x;

    // Phase A: hlin = hiddens @ W_hidden^T + b_hidden -> out_co (temp)
    gemm_phase<0>(hiddens, (const unsigned short*)nullptr, W_hidden, b_hidden,
                  (const float*)nullptr, out_co, smem, bid);
    gridbar(flags, go, 1);
    // Phase B: raw scores -> ws
    if (bid < 224)
        scores_phase(maps, out_co, W_rect, b_rect, scores, smem, bid);
    gridbar(flags, go, 2);
    // Phase C: softmax (-> out_attn) + ctx (bf16 -> ws)
    softmax_ctx_phase(maps, scores, out_attn, ctx16, smem, bid);
    gridbar(flags, go, 3);
    // Phase D: out_co = (ctx @ W_co^T + b_co) * hiddens
    gemm_phase<1>((const float*)nullptr, ctx16, W_co, b_co, hiddens, out_co, smem, bid);
}

extern "C" void kernel_launch(void* const* d_in, const int* in_sizes, int n_in,
                              void* d_out, int out_size, void* d_ws, size_t ws_size,
                              hipStream_t stream)
{
    const float* maps     = (const float*)d_in[0];
    const float* hiddens  = (const float*)d_in[1];
    const float* W_hidden = (const float*)d_in[2];
    const float* b_hidden = (const float*)d_in[3];
    const float* W_rect   = (const float*)d_in[4];
    const float* b_rect   = (const float*)d_in[5];
    const float* W_co     = (const float*)d_in[6];
    const float* b_co     = (const float*)d_in[7];

    float* out_co   = (float*)d_out;                    // (512,512): hlin, then final
    float* out_attn = out_co + (size_t)512 * 512;       // (512,196)

    char* ws = (char*)d_ws;
    float*          scores = (float*)(ws);                          // 401 KB
    unsigned short* ctx16  = (unsigned short*)(ws + (1 << 20));     // 512 KB
    int*            flags  = (int*)(ws + (4 << 20));                // 256*128B
    int*            go     = (int*)(ws + (4 << 20) + NBLK * 128 + 128);

    hipLaunchKernelGGL(coatt_mega_kernel, dim3(NBLK), dim3(256), 0, stream,
                       maps, hiddens, W_hidden, b_hidden, W_rect, b_rect,
                       W_co, b_co, out_co, out_attn, scores, ctx16, flags, go);
}

// Round 10
// 131.864 us; speedup vs baseline: 1.3841x; 1.3683x over previous
//
#include <hip/hip_runtime.h>
#include <math.h>

// B=16,H=14,W=14,D=512, L=32, HID=512, A=512. fp32 in/out; bf16 in MFMA GEMM phases.
// Single-node mega-kernel: 256 blocks x 256 threads, 4 phases with a master-block
// grid barrier. R10: spin with RELAXED agent loads (no per-poll cache invalidate);
// exactly ONE acquire fence after the spin exits. 0xAA ws poison reads as negative
// int and epochs are monotone positives -> no memset node needed.
#define NBLK 256

typedef __attribute__((ext_vector_type(8))) short short8;
typedef __attribute__((ext_vector_type(4))) float f32x4;

__device__ __forceinline__ unsigned f2bf_u(float x) {
    union { float f; unsigned u; } c; c.f = x;
    return (c.u + 0x7FFFu + ((c.u >> 16) & 1u)) >> 16;   // RNE, finite inputs
}
__device__ __forceinline__ unsigned short f2bf(float x) { return (unsigned short)f2bf_u(x); }
__device__ __forceinline__ unsigned pack2(float lo, float hi) {
    return f2bf_u(lo) | (f2bf_u(hi) << 16);
}
__device__ __forceinline__ uint4 pack8(const float4 a, const float4 b) {
    uint4 r;
    r.x = pack2(a.x, a.y); r.y = pack2(a.z, a.w);
    r.z = pack2(b.x, b.y); r.w = pack2(b.z, b.w);
    return r;
}

// flags[i*32] for block i (128B apart); go separate line.
// RELAXED spin (coherent read, no invalidate) + single ACQUIRE fence at exit.
__device__ __forceinline__ void gridbar(int* flags, int* go, int epoch) {
    __syncthreads();
    if (threadIdx.x == 0)
        __hip_atomic_store(&flags[blockIdx.x * 32], epoch, __ATOMIC_RELEASE, __HIP_MEMORY_SCOPE_AGENT);
    if (blockIdx.x == 0) {
        while (__hip_atomic_load(&flags[threadIdx.x * 32], __ATOMIC_RELAXED,
                                 __HIP_MEMORY_SCOPE_AGENT) < epoch) { __builtin_amdgcn_s_sleep(2); }
        __syncthreads();
        if (threadIdx.x == 0) {
            __builtin_amdgcn_fence(__ATOMIC_ACQUIRE, "agent");   // see all producers
            __hip_atomic_store(go, epoch, __ATOMIC_RELEASE, __HIP_MEMORY_SCOPE_AGENT);
        }
    }
    if (threadIdx.x == 0) {
        while (__hip_atomic_load(go, __ATOMIC_RELAXED, __HIP_MEMORY_SCOPE_AGENT) < epoch) {
            __builtin_amdgcn_s_sleep(2);
        }
        __builtin_amdgcn_fence(__ATOMIC_ACQUIRE, "agent");       // one invalidate total
    }
    __syncthreads();
}

// ---- GEMM phase: C = A(512,512)·B(512,512)^T + bias[n] [* hmul] ; bf16 MFMA ----
// 256 tiles of 32x32, exactly one per block; 4 waves split K (128 each) + LDS reduce.
template<int MODE>
__device__ __forceinline__ void gemm_phase(
    const float* __restrict__ Af, const unsigned short* __restrict__ Ab,
    const float* __restrict__ Bf, const float* __restrict__ bias,
    const float* __restrict__ hmul, float* __restrict__ C, char* smem, int bid)
{
    uint4* As = (uint4*)smem;               // 2048 slots (32KB)
    uint4* Bs = (uint4*)(smem + 32768);     // 2048 slots (32KB)
    float* red = (float*)smem;              // overlays As after sync (16KB)
    const int tid = threadIdx.x;

    const int m0 = (bid >> 4) * 32, n0 = (bid & 15) * 32;
    __syncthreads();
    #pragma unroll
    for (int j = 0; j < 8; ++j) {
        const int S = tid + 256 * j;
        const int i = S >> 6, ln = S & 63;
        const int t = i & 1, s = i >> 1;
        const int row  = t * 16 + (ln & 15);
        const int col8 = s * 4 + (ln >> 4);
        uint4 av;
        if (MODE == 0) {
            const float* ap = Af + (size_t)(m0 + row) * 512 + col8 * 8;
            av = pack8(*(const float4*)ap, *(const float4*)(ap + 4));
        } else {
            av = *(const uint4*)(Ab + (size_t)(m0 + row) * 512 + col8 * 8);
        }
        const float* bp = Bf + (size_t)(n0 + row) * 512 + col8 * 8;
        As[S] = av;
        Bs[S] = pack8(*(const float4*)bp, *(const float4*)(bp + 4));
    }
    __syncthreads();

    const int w = tid >> 6, ln = tid & 63;
    f32x4 acc[4];                            // fo = tm*2+tn
    #pragma unroll
    for (int fo = 0; fo < 4; ++fo) acc[fo] = (f32x4){0.f,0.f,0.f,0.f};
    #pragma unroll
    for (int sl = 0; sl < 4; ++sl) {
        const int s = 4 * w + sl;
        const short8 a0 = *(const short8*)&As[(2*s+0)*64 + ln];
        const short8 a1 = *(const short8*)&As[(2*s+1)*64 + ln];
        const short8 b0 = *(const short8*)&Bs[(2*s+0)*64 + ln];
        const short8 b1 = *(const short8*)&Bs[(2*s+1)*64 + ln];
        acc[0] = __builtin_amdgcn_mfma_f32_16x16x32_bf16(a0, b0, acc[0], 0, 0, 0);
        acc[1] = __builtin_amdgcn_mfma_f32_16x16x32_bf16(a0, b1, acc[1], 0, 0, 0);
        acc[2] = __builtin_amdgcn_mfma_f32_16x16x32_bf16(a1, b0, acc[2], 0, 0, 0);
        acc[3] = __builtin_amdgcn_mfma_f32_16x16x32_bf16(a1, b1, acc[3], 0, 0, 0);
    }
    __syncthreads();                         // done reading As/Bs
    #pragma unroll
    for (int fo = 0; fo < 4; ++fo)
        #pragma unroll
        for (int r = 0; r < 4; ++r)
            red[w*1024 + fo*256 + r*64 + ln] = acc[fo][r];
    __syncthreads();
    #pragma unroll
    for (int j = 0; j < 4; ++j) {
        const int o = tid + 256 * j;
        float v = red[o] + red[1024 + o] + red[2048 + o] + red[3072 + o];
        const int fo = o >> 8, r = (o >> 6) & 3, l2 = o & 63;
        // C/D layout: col = lane&15, row = (lane>>4)*4 + reg [m89-verified]
        const int m = m0 + (fo >> 1) * 16 + ((l2 >> 4) << 2) + r;
        const int n = n0 + (fo & 1) * 16 + (l2 & 15);
        v += bias[n];
        if (MODE == 1) v *= hmul[(size_t)m * 512 + n];
        C[(size_t)m * 512 + n] = v;
    }
}

// ---- scores phase: bid<224 -> (b = bid/14, ptile = bid%14). ----
// f,w in registers; hlin staged flat in LDS; column rotation (j+2kc)&7 kills conflicts.
__device__ __forceinline__ void scores_phase(
    const float* __restrict__ maps, const float* __restrict__ hlin,
    const float* __restrict__ W_rect, const float* __restrict__ b_rect,
    float* __restrict__ scores_out, char* smem, int bid)
{
    float* hls  = (float*)smem;              // 32*512 fp32 = 64KB
    float* redb = (float*)smem;              // overlays hls after main loop
    const int tid = threadIdx.x;
    const int b = bid / 14, p0 = (bid % 14) * 14;
    const int kc = tid >> 4, pslot = tid & 15;
    const int p = p0 + (pslot < 14 ? pslot : 13);

    __syncthreads();
    const float4* hg = (const float4*)(hlin + (size_t)b * 32 * 512);
    float4* h4 = (float4*)hls;
    #pragma unroll
    for (int j = 0; j < 16; ++j) h4[tid + 256 * j] = hg[tid + 256 * j];

    int cofs[8];
    float4 fr[8], wr[8];
    const float* fb = maps + ((size_t)b * 196 + p) * 512 + kc * 32;
    const float* wb = W_rect + kc * 32;
    #pragma unroll
    for (int j = 0; j < 8; ++j) {
        cofs[j] = 4 * ((j + 2 * kc) & 7);
        fr[j] = *(const float4*)(fb + cofs[j]);
        wr[j] = *(const float4*)(wb + cofs[j]);
    }
    __syncthreads();

    float acc[32];
    for (int l = 0; l < 32; ++l) {
        const float* hrow = hls + l * 512 + kc * 32;
        float s0 = 0.f, s1 = 0.f, s2 = 0.f, s3 = 0.f;
        #pragma unroll
        for (int j = 0; j < 8; ++j) {
            const float4 h = *(const float4*)(hrow + cofs[j]);
            const float4 f = fr[j], w = wr[j];
            s0 += fmaxf(f.x + h.x, 0.f) * w.x;
            s1 += fmaxf(f.y + h.y, 0.f) * w.y;
            s2 += fmaxf(f.z + h.z, 0.f) * w.z;
            s3 += fmaxf(f.w + h.w, 0.f) * w.w;
        }
        acc[l] = (s0 + s1) + (s2 + s3);
    }
    __syncthreads();                         // done reading hls
    // bank-rotated partial layout: addr = pslot*545 + l*17 + kc
    #pragma unroll 4
    for (int l = 0; l < 32; ++l)
        redb[pslot * 545 + l * 17 + kc] = acc[l];
    __syncthreads();
    const float br = b_rect[0];
    for (int q = tid; q < 448; q += 256) {
        const int pp = q >> 5, l = q & 31;
        const float* rb = redb + pp * 545 + l * 17;
        float s = 0.f;
        #pragma unroll
        for (int k = 0; k < 16; ++k) s += rb[k];
        scores_out[((size_t)b * 32 + l) * 196 + p0 + pp] = s + br;
    }
}

// ---- softmax + ctx phase: 256 tiles (16 b x 16 dtiles), one per block ----
__device__ __forceinline__ void softmax_ctx_phase(
    const float* __restrict__ maps, const float* __restrict__ scores,
    float* __restrict__ attn_out, unsigned short* __restrict__ ctx_out,
    char* smem, int bid)
{
    float* ft = (float*)smem;                // [196][36] = 28224 B
    float* at = (float*)(smem + 28224);      // [32][204] = 26112 B
    const int tid = threadIdx.x;

    const int b = bid >> 4, d0 = (bid & 15) * 32;
    __syncthreads();
    const float* fbase = maps + (size_t)b * 196 * 512 + d0;
    for (int fidx = tid; fidx < 1568; fidx += 256) {   // 196*32/4
        const int pp = fidx >> 3, q = fidx & 7;
        *(float4*)&ft[pp * 36 + q * 4] = *(const float4*)(fbase + (size_t)pp * 512 + q * 4);
    }
    const float4* sbase4 = (const float4*)(scores + (size_t)b * 32 * 196);
    for (int fidx = tid; fidx < 1568; fidx += 256) {   // 32 rows x 49 float4
        const int r = fidx / 49, c4 = fidx - r * 49;
        *(float4*)&at[r * 204 + c4 * 4] = sbase4[fidx];
    }
    __syncthreads();

    const int wave = tid >> 6, lane = tid & 63;
    #pragma unroll
    for (int rr = 0; rr < 8; ++rr) {
        const int row = wave * 8 + rr;
        float v[4];
        #pragma unroll
        for (int i = 0; i < 4; ++i) {
            const int pp = lane + 64 * i;
            v[i] = (pp < 196) ? at[row * 204 + pp] : -INFINITY;
        }
        float m = fmaxf(fmaxf(v[0], v[1]), fmaxf(v[2], v[3]));
        for (int off = 32; off > 0; off >>= 1) m = fmaxf(m, __shfl_down(m, off));
        m = __shfl(m, 0);
        float e[4], s = 0.f;
        #pragma unroll
        for (int i = 0; i < 4; ++i) {
            const int pp = lane + 64 * i;
            e[i] = (pp < 196) ? __expf(v[i] - m) : 0.f;
            s += e[i];
        }
        for (int off = 32; off > 0; off >>= 1) s += __shfl_down(s, off);
        s = __shfl(s, 0);
        const float inv = 1.f / s;
        #pragma unroll
        for (int i = 0; i < 4; ++i) {
            const int pp = lane + 64 * i;
            if (pp < 196) at[row * 204 + pp] = e[i] * inv;
        }
    }
    __syncthreads();

    if ((bid & 15) == 0) {
        float4* ao4 = (float4*)(attn_out + (size_t)b * 32 * 196);
        for (int fidx = tid; fidx < 1568; fidx += 256) {
            const int r = fidx / 49, c4 = fidx - r * 49;
            ao4[fidx] = *(const float4*)&at[r * 204 + c4 * 4];
        }
    }

    const int l = tid >> 3, d4 = tid & 7;
    float ax = 0.f, ay = 0.f, az = 0.f, aw = 0.f;
    for (int p4 = 0; p4 < 49; ++p4) {
        const float4 a4 = *(const float4*)&at[l * 204 + p4 * 4];
        const float4 f0 = *(const float4*)&ft[(p4 * 4 + 0) * 36 + d4 * 4];
        const float4 f1 = *(const float4*)&ft[(p4 * 4 + 1) * 36 + d4 * 4];
        const float4 f2 = *(const float4*)&ft[(p4 * 4 + 2) * 36 + d4 * 4];
        const float4 f3 = *(const float4*)&ft[(p4 * 4 + 3) * 36 + d4 * 4];
        ax += a4.x * f0.x + a4.y * f1.x + a4.z * f2.x + a4.w * f3.x;
        ay += a4.x * f0.y + a4.y * f1.y + a4.z * f2.y + a4.w * f3.y;
        az += a4.x * f0.z + a4.y * f1.z + a4.z * f2.z + a4.w * f3.z;
        aw += a4.x * f0.w + a4.y * f1.w + a4.z * f2.w + a4.w * f3.w;
    }
    ushort4 o;
    o.x = f2bf(ax); o.y = f2bf(ay); o.z = f2bf(az); o.w = f2bf(aw);
    *(ushort4*)(ctx_out + ((size_t)b * 32 + l) * 512 + d0 + d4 * 4) = o;
    __syncthreads();
}

__global__ __launch_bounds__(256) void coatt_mega_kernel(
    const float* __restrict__ maps, const float* __restrict__ hiddens,
    const float* __restrict__ W_hidden, const float* __restrict__ b_hidden,
    const float* __restrict__ W_rect, const float* __restrict__ b_rect,
    const float* __restrict__ W_co, const float* __restrict__ b_co,
    float* __restrict__ out_co, float* __restrict__ out_attn,
    float* __restrict__ scores, unsigned short* __restrict__ ctx16,
    int* __restrict__ flags, int* __restrict__ go)
{
    __shared__ __align__(16) char smem[65536];
    const int bid = blockIdx.x;

    // Phase A: hlin = hiddens @ W_hidden^T + b_hidden -> out_co (temp)
    gemm_phase<0>(hiddens, (const unsigned short*)nullptr, W_hidden, b_hidden,
                  (const float*)nullptr, out_co, smem, bid);
    gridbar(flags, go, 1);
    // Phase B: raw scores -> ws
    if (bid < 224)
        scores_phase(maps, out_co, W_rect, b_rect, scores, smem, bid);
    gridbar(flags, go, 2);
    // Phase C: softmax (-> out_attn) + ctx (bf16 -> ws)
    softmax_ctx_phase(maps, scores, out_attn, ctx16, smem, bid);
    gridbar(flags, go, 3);
    // Phase D: out_co = (ctx @ W_co^T + b_co) * hiddens
    gemm_phase<1>((const float*)nullptr, ctx16, W_co, b_co, hiddens, out_co, smem, bid);
}

extern "C" void kernel_launch(void* const* d_in, const int* in_sizes, int n_in,
                              void* d_out, int out_size, void* d_ws, size_t ws_size,
                              hipStream_t stream)
{
    const float* maps     = (const float*)d_in[0];
    const float* hiddens  = (const float*)d_in[1];
    const float* W_hidden = (const float*)d_in[2];
    const float* b_hidden = (const float*)d_in[3];
    const float* W_rect   = (const float*)d_in[4];
    const float* b_rect   = (const float*)d_in[5];
    const float* W_co     = (const float*)d_in[6];
    const float* b_co     = (const float*)d_in[7];

    float* out_co   = (float*)d_out;                    // (512,512): hlin, then final
    float* out_attn = out_co + (size_t)512 * 512;       // (512,196)

    char* ws = (char*)d_ws;
    float*          scores = (float*)(ws);                          // 401 KB
    unsigned short* ctx16  = (unsigned short*)(ws + (1 << 20));     // 512 KB
    int*            flags  = (int*)(ws + (4 << 20));                // 256*128B
    int*            go     = (int*)(ws + (4 << 20) + NBLK * 128 + 128);

    hipLaunchKernelGGL(coatt_mega_kernel, dim3(NBLK), dim3(256), 0, stream,
                       maps, hiddens, W_hidden, b_hidden, W_rect, b_rect,
                       W_co, b_co, out_co, out_attn, scores, ctx16, flags, go);
}